// Round 3
// baseline (145.716 us; speedup 1.0000x reference)
//
#include <hip/hip_runtime.h>
#include <math.h>

#define CH 64
#define TT 1000
#define NTRI 2080

typedef __attribute__((ext_vector_type(8))) short bf16x8;
typedef __attribute__((ext_vector_type(4))) float f32x4;
typedef __attribute__((ext_vector_type(4))) unsigned short u16x4;

__device__ __forceinline__ unsigned short f2bf(float f) {
    unsigned u = __builtin_bit_cast(unsigned, f);
    u += 0x7FFFu + ((u >> 16) & 1u);          // round-to-nearest-even
    return (unsigned short)(u >> 16);
}
__device__ __forceinline__ float bf2f(unsigned short h) {
    unsigned u = ((unsigned)h) << 16;
    return __builtin_bit_cast(float, u);
}
// element (r,c) of a [64][64] bf16 array, 16B-chunk XOR swizzle (2-way max)
__device__ __forceinline__ int sidx(int r, int c) {
    return (r << 6) + ((((c >> 3) ^ (r & 7)) << 3) | (c & 7));
}
// fragment base: 8 consecutive bf16 of row r, chunk ch (ch = k/8)
__device__ __forceinline__ int fidx(int r, int ch) {
    return (r << 6) + ((ch ^ (r & 7)) << 3);
}

// 64x64 * 64x64 symmetric-operand matmul band: wave w computes rows [16w,16w+16).
// A, B given as bf16 hi/lo pairs in swizzled layout. acc[c] += A*B for col-band c.
// Split-2 bf16: (Ah+Al)(Bh+Bl) ~ AhBh + AhBl + AlBh.
__device__ __forceinline__ void mm64(const unsigned short* Ah, const unsigned short* Al,
                                     const unsigned short* Bh, const unsigned short* Bl,
                                     int w, int l, f32x4* acc) {
    const int lc = l & 15, hq = l >> 4;
    const int ar = (w << 4) + lc;
    bf16x8 ah[2], al[2];
    #pragma unroll
    for (int ks = 0; ks < 2; ++ks) {
        ah[ks] = *(const bf16x8*)&Ah[fidx(ar, ks * 4 + hq)];
        al[ks] = *(const bf16x8*)&Al[fidx(ar, ks * 4 + hq)];
    }
    #pragma unroll
    for (int c = 0; c < 4; ++c) {
        const int br = (c << 4) + lc;
        #pragma unroll
        for (int ks = 0; ks < 2; ++ks) {
            bf16x8 bh = *(const bf16x8*)&Bh[fidx(br, ks * 4 + hq)];
            bf16x8 bl = *(const bf16x8*)&Bl[fidx(br, ks * 4 + hq)];
            acc[c] = __builtin_amdgcn_mfma_f32_16x16x32_bf16(ah[ks], bh, acc[c], 0, 0, 0);
            acc[c] = __builtin_amdgcn_mfma_f32_16x16x32_bf16(ah[ks], bl, acc[c], 0, 0, 0);
            acc[c] = __builtin_amdgcn_mfma_f32_16x16x32_bf16(al[ks], bh, acc[c], 0, 0, 0);
        }
    }
}

// ================= Kernel A: covariance only (streaming, no compute tail) ======
__global__ __launch_bounds__(256, 4) void cov_kernel(const float* __restrict__ x,
                                                     float* __restrict__ covw) {
    const int m   = blockIdx.x;
    const int tid = threadIdx.x;
    const float* xp = x + (size_t)m * (CH * TT);

    __shared__ __align__(16) unsigned short smem[16384];
    unsigned short* const B0h = smem;
    unsigned short* const B0l = smem + 4096;
    unsigned short* const B1h = smem + 8192;
    unsigned short* const B1l = smem + 12288;
    __shared__ float sRed[CH];

    const int w  = tid >> 6;
    const int l  = tid & 63;
    const int lc = l & 15;
    const int hq = l >> 4;

    const f32x4 z4 = {0.f, 0.f, 0.f, 0.f};
    f32x4 acc[4] = {z4, z4, z4, z4};

    const int srow = tid >> 2, sq = tid & 3;
    const float* xrow = xp + srow * TT;
    float psum = 0.f;

    // prologue: prefetch tile 0 (cols 0..63, all < TT)
    float4 pf0 = *(const float4*)&xrow[sq * 4];
    float4 pf1 = *(const float4*)&xrow[sq * 4 + 16];
    float4 pf2 = *(const float4*)&xrow[sq * 4 + 32];
    float4 pf3 = *(const float4*)&xrow[sq * 4 + 48];

    for (int t = 0; t < 16; ++t) {
        unsigned short* Xh = (t & 1) ? B1h : B0h;
        unsigned short* Xl = (t & 1) ? B1l : B0l;

        float4 vv[4] = {pf0, pf1, pf2, pf3};
        #pragma unroll
        for (int q4 = 0; q4 < 4; ++q4) {
            float4 v = vv[q4];
            psum += v.x + v.y + v.z + v.w;
            const int kl = sq * 4 + q4 * 16;
            u16x4 hv, lv;
            hv[0] = f2bf(v.x); lv[0] = f2bf(v.x - bf2f(hv[0]));
            hv[1] = f2bf(v.y); lv[1] = f2bf(v.y - bf2f(hv[1]));
            hv[2] = f2bf(v.z); lv[2] = f2bf(v.z - bf2f(hv[2]));
            hv[3] = f2bf(v.w); lv[3] = f2bf(v.w - bf2f(hv[3]));
            const int idx = (srow << 6) + ((((kl >> 3) ^ (srow & 7)) << 3) | (kl & 7));
            *(u16x4*)&Xh[idx] = hv;
            *(u16x4*)&Xl[idx] = lv;
        }

        if (t < 15) {
            const int kb = ((t + 1) << 6) + sq * 4;
            pf0 = (kb      < TT) ? *(const float4*)&xrow[kb]      : make_float4(0.f, 0.f, 0.f, 0.f);
            pf1 = (kb + 16 < TT) ? *(const float4*)&xrow[kb + 16] : make_float4(0.f, 0.f, 0.f, 0.f);
            pf2 = (kb + 32 < TT) ? *(const float4*)&xrow[kb + 32] : make_float4(0.f, 0.f, 0.f, 0.f);
            pf3 = (kb + 48 < TT) ? *(const float4*)&xrow[kb + 48] : make_float4(0.f, 0.f, 0.f, 0.f);
        }

        // drain only LDS writes (NOT the prefetch vmcnt), then raw barrier.
        // Safe: stores(t) target buf[t&1], last read by mm64(t-2); every wave's
        // mm64(t-2) ds_reads drained at its own lgkmcnt(0) before barrier(t-1).
        asm volatile("s_waitcnt lgkmcnt(0)" ::: "memory");
        __builtin_amdgcn_s_barrier();
        __builtin_amdgcn_sched_barrier(0);

        mm64(Xh, Xl, Xh, Xl, w, l, acc);
    }

    psum += __shfl_xor(psum, 1, 64);
    psum += __shfl_xor(psum, 2, 64);
    if (sq == 0) sRed[srow] = psum;
    __syncthreads();

    const float invT = 1.f / (float)TT, invTm1 = 1.f / (float)(TT - 1);
    float Srow[4], Scol[4];
    #pragma unroll
    for (int r = 0; r < 4; ++r) Srow[r] = sRed[(w << 4) + hq * 4 + r];
    #pragma unroll
    for (int c = 0; c < 4; ++c) Scol[c] = sRed[(c << 4) + lc];

    float* cw = covw + (size_t)m * (CH * CH);
    #pragma unroll
    for (int c = 0; c < 4; ++c)
        #pragma unroll
        for (int r = 0; r < 4; ++r) {
            const int row = (w << 4) + hq * 4 + r, col = (c << 4) + lc;
            cw[row * CH + col] = (acc[c][r] - Srow[r] * Scol[c] * invT) * invTm1;
        }
}

// ================= Kernel B: matrix log from cov (L3-resident input) ===========
__global__ __launch_bounds__(256, 4) void logm_kernel(const float* __restrict__ covw,
                                                      float* __restrict__ out) {
    const int m   = blockIdx.x;
    const int tid = threadIdx.x;

    __shared__ __align__(16) unsigned short smem[16384];
    unsigned short* const B0h = smem;        // E, later E^3
    unsigned short* const B0l = smem + 4096;
    unsigned short* const B1h = smem + 8192; // E^2, later R
    unsigned short* const B1l = smem + 12288;
    __shared__ float sTr[4];

    const int w  = tid >> 6;
    const int l  = tid & 63;
    const int lc = l & 15;
    const int hq = l >> 4;

    const f32x4 z4 = {0.f, 0.f, 0.f, 0.f};

    // load cov (same thread->element mapping as cov_kernel's store)
    const float* cw = covw + (size_t)m * (CH * CH);
    float covv[4][4];
    float trp = 0.f;
    #pragma unroll
    for (int c = 0; c < 4; ++c)
        #pragma unroll
        for (int r = 0; r < 4; ++r) {
            const int row = (w << 4) + hq * 4 + r, col = (c << 4) + lc;
            covv[c][r] = cw[row * CH + col];
            if (c == w && lc == hq * 4 + r) trp += covv[c][r];
        }
    trp += __shfl_xor(trp, 1, 64);  trp += __shfl_xor(trp, 2, 64);
    trp += __shfl_xor(trp, 4, 64);  trp += __shfl_xor(trp, 8, 64);
    trp += __shfl_xor(trp, 16, 64); trp += __shfl_xor(trp, 32, 64);
    if (l == 0) sTr[w] = trp;
    __syncthreads();
    const float s    = (sTr[0] + sTr[1] + sTr[2] + sTr[3]) * (1.f / 64.f);
    const float invs = 1.f / s;
    const float logs = logf(s);

    // E = cov/s - I -> B0
    float Ev[4][4], e2v[4][4];
    #pragma unroll
    for (int c = 0; c < 4; ++c)
        #pragma unroll
        for (int r = 0; r < 4; ++r) {
            const int row = (w << 4) + hq * 4 + r, col = (c << 4) + lc;
            const float e = covv[c][r] * invs - ((row == col) ? 1.f : 0.f);
            Ev[c][r] = e;
            const unsigned short h = f2bf(e);
            B0h[sidx(row, col)] = h;
            B0l[sidx(row, col)] = f2bf(e - bf2f(h));
        }
    __syncthreads();

    // E^2 -> B1
    f32x4 a2[4] = {z4, z4, z4, z4};
    mm64(B0h, B0l, B0h, B0l, w, l, a2);
    #pragma unroll
    for (int c = 0; c < 4; ++c)
        #pragma unroll
        for (int r = 0; r < 4; ++r) {
            const int row = (w << 4) + hq * 4 + r, col = (c << 4) + lc;
            const float v = a2[c][r];
            e2v[c][r] = v;
            const unsigned short h = f2bf(v);
            B1h[sidx(row, col)] = h;
            B1l[sidx(row, col)] = f2bf(v - bf2f(h));
        }
    __syncthreads();

    // E^3 = E * E^2
    f32x4 a3[4] = {z4, z4, z4, z4};
    mm64(B0h, B0l, B1h, B1l, w, l, a3);
    __syncthreads();   // all reads of E (B0) and E^2 (B1) complete before overwrite

    // P3 = E^3 -> B0 (over E); R init -> B1 (over E^2)
    #pragma unroll
    for (int c = 0; c < 4; ++c)
        #pragma unroll
        for (int r = 0; r < 4; ++r) {
            const int row = (w << 4) + hq * 4 + r, col = (c << 4) + lc;
            const float e3 = a3[c][r];
            unsigned short h = f2bf(e3);
            B0h[sidx(row, col)] = h;
            B0l[sidx(row, col)] = f2bf(e3 - bf2f(h));
            float rv = (1.f/15.f) * e3 + (-1.f/14.f) * e2v[c][r] + (1.f/13.f) * Ev[c][r]
                     + ((row == col) ? (-1.f/12.f) : 0.f);
            h = f2bf(rv);
            B1h[sidx(row, col)] = h;
            B1l[sidx(row, col)] = f2bf(rv - bf2f(h));
        }
    __syncthreads();

    // Horner: R = E^3*R + (c0 I + c1 E + c2 E^2), j = 3,2,1
    const float CJ[3][3] = {
        { 1.f/9.f, -1.f/10.f,  1.f/11.f },
        {-1.f/6.f,  1.f/7.f,  -1.f/8.f  },
        { 1.f/3.f, -1.f/4.f,   1.f/5.f  },
    };
    #pragma unroll
    for (int jj = 0; jj < 3; ++jj) {
        f32x4 ar[4] = {z4, z4, z4, z4};
        mm64(B0h, B0l, B1h, B1l, w, l, ar);
        __syncthreads();
        const float c0 = CJ[jj][0], c1 = CJ[jj][1], c2 = CJ[jj][2];
        #pragma unroll
        for (int c = 0; c < 4; ++c)
            #pragma unroll
            for (int r = 0; r < 4; ++r) {
                const int row = (w << 4) + hq * 4 + r, col = (c << 4) + lc;
                float rv = ar[c][r] + c1 * Ev[c][r] + c2 * e2v[c][r]
                         + ((row == col) ? c0 : 0.f);
                const unsigned short h = f2bf(rv);
                B1h[sidx(row, col)] = h;
                B1l[sidx(row, col)] = f2bf(rv - bf2f(h));
            }
        __syncthreads();
    }

    // final: p = E^3*R + E - 0.5 E^2 ; logm = p + log(s) I, triu only
    f32x4 aF[4] = {z4, z4, z4, z4};
    mm64(B0h, B0l, B1h, B1l, w, l, aF);
    const size_t ob = (size_t)m * NTRI;
    #pragma unroll
    for (int c = 0; c < 4; ++c)
        #pragma unroll
        for (int r = 0; r < 4; ++r) {
            const int row = (w << 4) + hq * 4 + r, col = (c << 4) + lc;
            if (row <= col) {
                float v = aF[c][r] + Ev[c][r] - 0.5f * e2v[c][r]
                        + ((row == col) ? logs : 0.f);
                out[ob + row * (2 * CH - row + 1) / 2 + (col - row)] = v;
            }
        }
}

// ================= Fused fallback (R0 structure, known-good 126 µs) ============
__global__ __launch_bounds__(256, 4) void spd_logm_fused(const float* __restrict__ x,
                                                         float* __restrict__ out) {
    const int m   = blockIdx.x;
    const int tid = threadIdx.x;
    const float* xp = x + (size_t)m * (CH * TT);

    __shared__ __align__(16) unsigned short smem[16384];
    unsigned short* const B0h = smem;
    unsigned short* const B0l = smem + 4096;
    unsigned short* const B1h = smem + 8192;
    unsigned short* const B1l = smem + 12288;
    __shared__ float sRed[CH];
    __shared__ float sTr[4];

    const int w  = tid >> 6;
    const int l  = tid & 63;
    const int lc = l & 15;
    const int hq = l >> 4;

    const f32x4 z4 = {0.f, 0.f, 0.f, 0.f};
    f32x4 acc[4] = {z4, z4, z4, z4};

    const int srow = tid >> 2, sq = tid & 3;
    const float* xrow = xp + srow * TT;
    float psum = 0.f;

    float4 pf0 = *(const float4*)&xrow[sq * 4];
    float4 pf1 = *(const float4*)&xrow[sq * 4 + 16];
    float4 pf2 = *(const float4*)&xrow[sq * 4 + 32];
    float4 pf3 = *(const float4*)&xrow[sq * 4 + 48];

    for (int t = 0; t < 16; ++t) {
        unsigned short* Xh = (t & 1) ? B1h : B0h;
        unsigned short* Xl = (t & 1) ? B1l : B0l;

        float4 vv[4] = {pf0, pf1, pf2, pf3};
        #pragma unroll
        for (int q4 = 0; q4 < 4; ++q4) {
            float4 v = vv[q4];
            psum += v.x + v.y + v.z + v.w;
            const int kl = sq * 4 + q4 * 16;
            u16x4 hv, lv;
            hv[0] = f2bf(v.x); lv[0] = f2bf(v.x - bf2f(hv[0]));
            hv[1] = f2bf(v.y); lv[1] = f2bf(v.y - bf2f(hv[1]));
            hv[2] = f2bf(v.z); lv[2] = f2bf(v.z - bf2f(hv[2]));
            hv[3] = f2bf(v.w); lv[3] = f2bf(v.w - bf2f(hv[3]));
            const int idx = (srow << 6) + ((((kl >> 3) ^ (srow & 7)) << 3) | (kl & 7));
            *(u16x4*)&Xh[idx] = hv;
            *(u16x4*)&Xl[idx] = lv;
        }

        if (t < 15) {
            const int kb = ((t + 1) << 6) + sq * 4;
            pf0 = (kb      < TT) ? *(const float4*)&xrow[kb]      : make_float4(0.f, 0.f, 0.f, 0.f);
            pf1 = (kb + 16 < TT) ? *(const float4*)&xrow[kb + 16] : make_float4(0.f, 0.f, 0.f, 0.f);
            pf2 = (kb + 32 < TT) ? *(const float4*)&xrow[kb + 32] : make_float4(0.f, 0.f, 0.f, 0.f);
            pf3 = (kb + 48 < TT) ? *(const float4*)&xrow[kb + 48] : make_float4(0.f, 0.f, 0.f, 0.f);
        }

        asm volatile("s_waitcnt lgkmcnt(0)" ::: "memory");
        __builtin_amdgcn_s_barrier();
        __builtin_amdgcn_sched_barrier(0);

        mm64(Xh, Xl, Xh, Xl, w, l, acc);
    }

    psum += __shfl_xor(psum, 1, 64);
    psum += __shfl_xor(psum, 2, 64);
    if (sq == 0) sRed[srow] = psum;
    __syncthreads();

    const float invT = 1.f / (float)TT, invTm1 = 1.f / (float)(TT - 1);
    float Srow[4], Scol[4];
    #pragma unroll
    for (int r = 0; r < 4; ++r) Srow[r] = sRed[(w << 4) + hq * 4 + r];
    #pragma unroll
    for (int c = 0; c < 4; ++c) Scol[c] = sRed[(c << 4) + lc];

    float covv[4][4];
    float trp = 0.f;
    #pragma unroll
    for (int c = 0; c < 4; ++c)
        #pragma unroll
        for (int r = 0; r < 4; ++r) {
            covv[c][r] = (acc[c][r] - Srow[r] * Scol[c] * invT) * invTm1;
            if (c == w && lc == hq * 4 + r) trp += covv[c][r];
        }
    trp += __shfl_xor(trp, 1, 64);  trp += __shfl_xor(trp, 2, 64);
    trp += __shfl_xor(trp, 4, 64);  trp += __shfl_xor(trp, 8, 64);
    trp += __shfl_xor(trp, 16, 64); trp += __shfl_xor(trp, 32, 64);
    if (l == 0) sTr[w] = trp;
    __syncthreads();
    const float s    = (sTr[0] + sTr[1] + sTr[2] + sTr[3]) * (1.f / 64.f);
    const float invs = 1.f / s;
    const float logs = logf(s);

    float Ev[4][4], e2v[4][4];
    #pragma unroll
    for (int c = 0; c < 4; ++c)
        #pragma unroll
        for (int r = 0; r < 4; ++r) {
            const int row = (w << 4) + hq * 4 + r, col = (c << 4) + lc;
            const float e = covv[c][r] * invs - ((row == col) ? 1.f : 0.f);
            Ev[c][r] = e;
            const unsigned short h = f2bf(e);
            B0h[sidx(row, col)] = h;
            B0l[sidx(row, col)] = f2bf(e - bf2f(h));
        }
    __syncthreads();

    f32x4 a2[4] = {z4, z4, z4, z4};
    mm64(B0h, B0l, B0h, B0l, w, l, a2);
    #pragma unroll
    for (int c = 0; c < 4; ++c)
        #pragma unroll
        for (int r = 0; r < 4; ++r) {
            const int row = (w << 4) + hq * 4 + r, col = (c << 4) + lc;
            const float v = a2[c][r];
            e2v[c][r] = v;
            const unsigned short h = f2bf(v);
            B1h[sidx(row, col)] = h;
            B1l[sidx(row, col)] = f2bf(v - bf2f(h));
        }
    __syncthreads();

    f32x4 a3[4] = {z4, z4, z4, z4};
    mm64(B0h, B0l, B1h, B1l, w, l, a3);
    __syncthreads();

    #pragma unroll
    for (int c = 0; c < 4; ++c)
        #pragma unroll
        for (int r = 0; r < 4; ++r) {
            const int row = (w << 4) + hq * 4 + r, col = (c << 4) + lc;
            const float e3 = a3[c][r];
            unsigned short h = f2bf(e3);
            B0h[sidx(row, col)] = h;
            B0l[sidx(row, col)] = f2bf(e3 - bf2f(h));
            float rv = (1.f/15.f) * e3 + (-1.f/14.f) * e2v[c][r] + (1.f/13.f) * Ev[c][r]
                     + ((row == col) ? (-1.f/12.f) : 0.f);
            h = f2bf(rv);
            B1h[sidx(row, col)] = h;
            B1l[sidx(row, col)] = f2bf(rv - bf2f(h));
        }
    __syncthreads();

    const float CJ[3][3] = {
        { 1.f/9.f, -1.f/10.f,  1.f/11.f },
        {-1.f/6.f,  1.f/7.f,  -1.f/8.f  },
        { 1.f/3.f, -1.f/4.f,   1.f/5.f  },
    };
    #pragma unroll
    for (int jj = 0; jj < 3; ++jj) {
        f32x4 ar[4] = {z4, z4, z4, z4};
        mm64(B0h, B0l, B1h, B1l, w, l, ar);
        __syncthreads();
        const float c0 = CJ[jj][0], c1 = CJ[jj][1], c2 = CJ[jj][2];
        #pragma unroll
        for (int c = 0; c < 4; ++c)
            #pragma unroll
            for (int r = 0; r < 4; ++r) {
                const int row = (w << 4) + hq * 4 + r, col = (c << 4) + lc;
                float rv = ar[c][r] + c1 * Ev[c][r] + c2 * e2v[c][r]
                         + ((row == col) ? c0 : 0.f);
                const unsigned short h = f2bf(rv);
                B1h[sidx(row, col)] = h;
                B1l[sidx(row, col)] = f2bf(rv - bf2f(h));
            }
        __syncthreads();
    }

    f32x4 aF[4] = {z4, z4, z4, z4};
    mm64(B0h, B0l, B1h, B1l, w, l, aF);
    const size_t ob = (size_t)m * NTRI;
    #pragma unroll
    for (int c = 0; c < 4; ++c)
        #pragma unroll
        for (int r = 0; r < 4; ++r) {
            const int row = (w << 4) + hq * 4 + r, col = (c << 4) + lc;
            if (row <= col) {
                float v = aF[c][r] + Ev[c][r] - 0.5f * e2v[c][r]
                        + ((row == col) ? logs : 0.f);
                out[ob + row * (2 * CH - row + 1) / 2 + (col - row)] = v;
            }
        }
}

extern "C" void kernel_launch(void* const* d_in, const int* in_sizes, int n_in,
                              void* d_out, int out_size, void* d_ws, size_t ws_size,
                              hipStream_t stream) {
    const float* x = (const float*)d_in[0];
    float* out = (float*)d_out;
    const int nm = in_sizes[0] / (CH * TT);   // B*F = 2048
    const size_t need = (size_t)nm * (CH * CH) * sizeof(float);  // 33.5 MB
    if (d_ws != nullptr && ws_size >= need) {
        float* covw = (float*)d_ws;
        cov_kernel<<<nm, 256, 0, stream>>>(x, covw);
        logm_kernel<<<nm, 256, 0, stream>>>(covw, out);
    } else {
        spd_logm_fused<<<nm, 256, 0, stream>>>(x, out);
    }
}

// Round 5
// 136.469 us; speedup vs baseline: 1.0678x; 1.0678x over previous
//
#include <hip/hip_runtime.h>
#include <math.h>

#define CH 64
#define TT 1000
#define NTRI 2080

typedef __attribute__((ext_vector_type(8))) short bf16x8;
typedef __attribute__((ext_vector_type(4))) float f32x4;
typedef __attribute__((ext_vector_type(4))) unsigned short u16x4;

__device__ __forceinline__ unsigned short f2bf(float f) {
    unsigned u = __builtin_bit_cast(unsigned, f);
    u += 0x7FFFu + ((u >> 16) & 1u);          // round-to-nearest-even
    return (unsigned short)(u >> 16);
}
__device__ __forceinline__ float bf2f(unsigned short h) {
    unsigned u = ((unsigned)h) << 16;
    return __builtin_bit_cast(float, u);
}
// element (r,c) of a [64][64] bf16 array, 16B-chunk XOR swizzle (2-way max)
__device__ __forceinline__ int sidx(int r, int c) {
    return (r << 6) + ((((c >> 3) ^ (r & 7)) << 3) | (c & 7));
}
// fragment base: 8 consecutive bf16 of row r, chunk ch (ch = k/8)
__device__ __forceinline__ int fidx(int r, int ch) {
    return (r << 6) + ((ch ^ (r & 7)) << 3);
}

// 64x64 * 64x64 symmetric-operand matmul band: wave w computes rows [16w,16w+16).
// A, B given as bf16 hi/lo pairs in swizzled layout. acc[c] += A*B for col-band c.
// Split-2 bf16: (Ah+Al)(Bh+Bl) ~ AhBh + AhBl + AlBh.
__device__ __forceinline__ void mm64(const unsigned short* Ah, const unsigned short* Al,
                                     const unsigned short* Bh, const unsigned short* Bl,
                                     int w, int l, f32x4* acc) {
    const int lc = l & 15, hq = l >> 4;
    const int ar = (w << 4) + lc;
    bf16x8 ah[2], al[2];
    #pragma unroll
    for (int ks = 0; ks < 2; ++ks) {
        ah[ks] = *(const bf16x8*)&Ah[fidx(ar, ks * 4 + hq)];
        al[ks] = *(const bf16x8*)&Al[fidx(ar, ks * 4 + hq)];
    }
    #pragma unroll
    for (int c = 0; c < 4; ++c) {
        const int br = (c << 4) + lc;
        #pragma unroll
        for (int ks = 0; ks < 2; ++ks) {
            bf16x8 bh = *(const bf16x8*)&Bh[fidx(br, ks * 4 + hq)];
            bf16x8 bl = *(const bf16x8*)&Bl[fidx(br, ks * 4 + hq)];
            acc[c] = __builtin_amdgcn_mfma_f32_16x16x32_bf16(ah[ks], bh, acc[c], 0, 0, 0);
            acc[c] = __builtin_amdgcn_mfma_f32_16x16x32_bf16(ah[ks], bl, acc[c], 0, 0, 0);
            acc[c] = __builtin_amdgcn_mfma_f32_16x16x32_bf16(al[ks], bh, acc[c], 0, 0, 0);
        }
    }
}

// LDS: exactly 32 KB -> 5 blocks/CU. sRed/sTr alias the dead B0 region between
// end of phase-1 and the E-write (protected by the post-`s` __syncthreads()).
__global__ __launch_bounds__(256, 5) void spd_logm_kernel(const float* __restrict__ x,
                                                          float* __restrict__ out) {
    const int m   = blockIdx.x;
    const int tid = threadIdx.x;
    const float* xp = x + (size_t)m * (CH * TT);

    __shared__ __align__(16) unsigned short smem[16384];   // 32768 B exactly
    unsigned short* const B0h = smem;
    unsigned short* const B0l = smem + 4096;
    unsigned short* const B1h = smem + 8192;
    unsigned short* const B1l = smem + 12288;
    float* const sRedf = (float*)smem;         // 64 floats, aliases B0h[0:512B)
    float* const sTrf  = ((float*)smem) + 64;  // 4 floats

    const int w  = tid >> 6;   // wave id -> row band [16w, 16w+16)
    const int l  = tid & 63;
    const int lc = l & 15;     // C-layout col within tile
    const int hq = l >> 4;     // C-layout row quad

    const f32x4 z4 = {0.f, 0.f, 0.f, 0.f};

    // ---------------- Phase 1: G = X * X^T via MFMA ----------------
    // Staging map: 16 lanes cover one row's 64-col tile slice (256 B contiguous
    // per row per instruction -> dense DRAM requests). Each thread handles rows
    // r0, r0+16, r0+32, r0+48 (pieces j=0..3).
    f32x4 acc[4] = {z4, z4, z4, z4};

    const int g16  = tid & 15;       // col group within row
    const int r0   = tid >> 4;       // base row (0..15)
    const int colf = g16 * 4;        // float col within tile
    const float* xr0 = xp + r0 * TT; // NOTE: colf is in kb_, not here (R3 bug: was added twice)
    // swizzled LDS index for (r0, colf); piece j adds j*1024 (rows +16 keep row&7)
    const int idx0 = (r0 << 6) + ((((colf >> 3) ^ (r0 & 7)) << 3) | (colf & 7));

    float psum[4] = {0.f, 0.f, 0.f, 0.f};
    float4 pf[4];

    #define ISSUE(T) do {                                                          \
        const int kb_ = ((T) << 6) + colf;                                         \
        const bool ok_ = kb_ < TT;                                                 \
        _Pragma("unroll")                                                          \
        for (int j = 0; j < 4; ++j)                                                \
            pf[j] = ok_ ? *(const float4*)(xr0 + j * (16 * TT) + kb_)              \
                        : make_float4(0.f, 0.f, 0.f, 0.f);                         \
    } while (0)

    #define STAGE(XH, XL) do {                                                     \
        _Pragma("unroll")                                                          \
        for (int j = 0; j < 4; ++j) {                                              \
            float4 v = pf[j];                                                      \
            psum[j] += v.x + v.y + v.z + v.w;                                      \
            u16x4 hv, lv;                                                          \
            hv[0] = f2bf(v.x); lv[0] = f2bf(v.x - bf2f(hv[0]));                    \
            hv[1] = f2bf(v.y); lv[1] = f2bf(v.y - bf2f(hv[1]));                    \
            hv[2] = f2bf(v.z); lv[2] = f2bf(v.z - bf2f(hv[2]));                    \
            hv[3] = f2bf(v.w); lv[3] = f2bf(v.w - bf2f(hv[3]));                    \
            *(u16x4*)&XH[idx0 + j * 1024] = hv;                                    \
            *(u16x4*)&XL[idx0 + j * 1024] = lv;                                    \
        }                                                                          \
    } while (0)

    ISSUE(0);   // prologue

    for (int t = 0; t < 16; ++t) {
        unsigned short* Xh = (t & 1) ? B1h : B0h;
        unsigned short* Xl = (t & 1) ? B1l : B0l;

        STAGE(Xh, Xl);                 // waits on pf's vmcnt here
        if (t < 15) ISSUE(t + 1);      // next tile's loads stay in flight

        // drain only LDS writes (NOT the prefetch vmcnt), then raw barrier.
        // Safe: stores(t) target buf[t&1], last read by mm64(t-2); every wave's
        // mm64(t-2) ds_reads drained at its own lgkmcnt(0) before barrier(t-1).
        asm volatile("s_waitcnt lgkmcnt(0)" ::: "memory");
        __builtin_amdgcn_s_barrier();
        __builtin_amdgcn_sched_barrier(0);

        mm64(Xh, Xl, Xh, Xl, w, l, acc);
    }
    #undef ISSUE
    #undef STAGE

    // row sums: 16 lanes per row -> xor-reduce within 16-lane group.
    // sRedf aliases B0 (dead: mm64(15) reads only B1; mm64(14) reads drained).
    #pragma unroll
    for (int j = 0; j < 4; ++j) {
        psum[j] += __shfl_xor(psum[j], 1, 64);
        psum[j] += __shfl_xor(psum[j], 2, 64);
        psum[j] += __shfl_xor(psum[j], 4, 64);
        psum[j] += __shfl_xor(psum[j], 8, 64);
    }
    if (g16 == 0) {
        #pragma unroll
        for (int j = 0; j < 4; ++j) sRedf[r0 + 16 * j] = psum[j];
    }
    __syncthreads();

    // ---------------- cov, trace, E ----------------
    const float invT = 1.f / (float)TT, invTm1 = 1.f / (float)(TT - 1);
    float Srow[4], Scol[4];
    #pragma unroll
    for (int r = 0; r < 4; ++r) Srow[r] = sRedf[(w << 4) + hq * 4 + r];
    #pragma unroll
    for (int c = 0; c < 4; ++c) Scol[c] = sRedf[(c << 4) + lc];

    float covv[4][4];
    float trp = 0.f;
    #pragma unroll
    for (int c = 0; c < 4; ++c)
        #pragma unroll
        for (int r = 0; r < 4; ++r) {
            covv[c][r] = (acc[c][r] - Srow[r] * Scol[c] * invT) * invTm1;
            if (c == w && lc == hq * 4 + r) trp += covv[c][r];
        }
    trp += __shfl_xor(trp, 1, 64);  trp += __shfl_xor(trp, 2, 64);
    trp += __shfl_xor(trp, 4, 64);  trp += __shfl_xor(trp, 8, 64);
    trp += __shfl_xor(trp, 16, 64); trp += __shfl_xor(trp, 32, 64);
    if (l == 0) sTrf[w] = trp;
    __syncthreads();
    const float s    = (sTrf[0] + sTrf[1] + sTrf[2] + sTrf[3]) * (1.f / 64.f);
    const float invs = 1.f / s;
    const float logs = logf(s);
    __syncthreads();   // sRed/sTr fully consumed before E overwrites their alias

    // E = cov/s - I -> B0
    float Ev[4][4], e2v[4][4];
    #pragma unroll
    for (int c = 0; c < 4; ++c)
        #pragma unroll
        for (int r = 0; r < 4; ++r) {
            const int row = (w << 4) + hq * 4 + r, col = (c << 4) + lc;
            const float e = covv[c][r] * invs - ((row == col) ? 1.f : 0.f);
            Ev[c][r] = e;
            const unsigned short h = f2bf(e);
            B0h[sidx(row, col)] = h;
            B0l[sidx(row, col)] = f2bf(e - bf2f(h));
        }
    __syncthreads();

    // ---------------- Phase 2: Paterson-Stockmeyer deg-15 ----------------
    // E^2 -> B1
    f32x4 a2[4] = {z4, z4, z4, z4};
    mm64(B0h, B0l, B0h, B0l, w, l, a2);
    #pragma unroll
    for (int c = 0; c < 4; ++c)
        #pragma unroll
        for (int r = 0; r < 4; ++r) {
            const int row = (w << 4) + hq * 4 + r, col = (c << 4) + lc;
            const float v = a2[c][r];
            e2v[c][r] = v;
            const unsigned short h = f2bf(v);
            B1h[sidx(row, col)] = h;
            B1l[sidx(row, col)] = f2bf(v - bf2f(h));
        }
    __syncthreads();

    // E^3 = E * E^2
    f32x4 a3[4] = {z4, z4, z4, z4};
    mm64(B0h, B0l, B1h, B1l, w, l, a3);
    __syncthreads();   // all reads of E (B0) and E^2 (B1) complete before overwrite

    // P3 = E^3 -> B0 (over E); R init = c12 I + c13 E + c14 E^2 + c15 E^3 -> B1
    #pragma unroll
    for (int c = 0; c < 4; ++c)
        #pragma unroll
        for (int r = 0; r < 4; ++r) {
            const int row = (w << 4) + hq * 4 + r, col = (c << 4) + lc;
            const float e3 = a3[c][r];
            unsigned short h = f2bf(e3);
            B0h[sidx(row, col)] = h;
            B0l[sidx(row, col)] = f2bf(e3 - bf2f(h));
            float rv = (1.f/15.f) * e3 + (-1.f/14.f) * e2v[c][r] + (1.f/13.f) * Ev[c][r]
                     + ((row == col) ? (-1.f/12.f) : 0.f);
            h = f2bf(rv);
            B1h[sidx(row, col)] = h;
            B1l[sidx(row, col)] = f2bf(rv - bf2f(h));
        }
    __syncthreads();

    // Horner: R = E^3*R + (c0 I + c1 E + c2 E^2), j = 3,2,1
    const float CJ[3][3] = {
        { 1.f/9.f, -1.f/10.f,  1.f/11.f },
        {-1.f/6.f,  1.f/7.f,  -1.f/8.f  },
        { 1.f/3.f, -1.f/4.f,   1.f/5.f  },
    };
    #pragma unroll
    for (int jj = 0; jj < 3; ++jj) {
        f32x4 ar[4] = {z4, z4, z4, z4};
        mm64(B0h, B0l, B1h, B1l, w, l, ar);
        __syncthreads();                      // all reads of old R complete
        const float c0 = CJ[jj][0], c1 = CJ[jj][1], c2 = CJ[jj][2];
        #pragma unroll
        for (int c = 0; c < 4; ++c)
            #pragma unroll
            for (int r = 0; r < 4; ++r) {
                const int row = (w << 4) + hq * 4 + r, col = (c << 4) + lc;
                float rv = ar[c][r] + c1 * Ev[c][r] + c2 * e2v[c][r]
                         + ((row == col) ? c0 : 0.f);
                const unsigned short h = f2bf(rv);
                B1h[sidx(row, col)] = h;
                B1l[sidx(row, col)] = f2bf(rv - bf2f(h));
            }
        __syncthreads();                      // new R visible
    }

    // final: p = E^3*R + E - 0.5 E^2 ; logm = p + log(s) I, triu only
    f32x4 aF[4] = {z4, z4, z4, z4};
    mm64(B0h, B0l, B1h, B1l, w, l, aF);
    const size_t ob = (size_t)m * NTRI;
    #pragma unroll
    for (int c = 0; c < 4; ++c)
        #pragma unroll
        for (int r = 0; r < 4; ++r) {
            const int row = (w << 4) + hq * 4 + r, col = (c << 4) + lc;
            if (row <= col) {
                float v = aF[c][r] + Ev[c][r] - 0.5f * e2v[c][r]
                        + ((row == col) ? logs : 0.f);
                out[ob + row * (2 * CH - row + 1) / 2 + (col - row)] = v;
            }
        }
}

extern "C" void kernel_launch(void* const* d_in, const int* in_sizes, int n_in,
                              void* d_out, int out_size, void* d_ws, size_t ws_size,
                              hipStream_t stream) {
    const float* x = (const float*)d_in[0];
    float* out = (float*)d_out;
    const int nm = in_sizes[0] / (CH * TT);   // B*F = 2048
    spd_logm_kernel<<<nm, 256, 0, stream>>>(x, out);
}

// Round 6
// 129.644 us; speedup vs baseline: 1.1240x; 1.0526x over previous
//
#include <hip/hip_runtime.h>
#include <math.h>

#define CH 64
#define TT 1000
#define NTRI 2080

typedef __attribute__((ext_vector_type(8))) short bf16x8;
typedef __attribute__((ext_vector_type(4))) float f32x4;
typedef __attribute__((ext_vector_type(4))) unsigned short u16x4;

__device__ __forceinline__ unsigned short f2bf(float f) {
    unsigned u = __builtin_bit_cast(unsigned, f);
    u += 0x7FFFu + ((u >> 16) & 1u);          // round-to-nearest-even
    return (unsigned short)(u >> 16);
}
__device__ __forceinline__ float bf2f(unsigned short h) {
    unsigned u = ((unsigned)h) << 16;
    return __builtin_bit_cast(float, u);
}
// element (r,c) of a [64][64] bf16 array, 16B-chunk XOR swizzle (2-way max)
__device__ __forceinline__ int sidx(int r, int c) {
    return (r << 6) + ((((c >> 3) ^ (r & 7)) << 3) | (c & 7));
}
// fragment base: 8 consecutive bf16 of row r, chunk ch (ch = k/8)
__device__ __forceinline__ int fidx(int r, int ch) {
    return (r << 6) + ((ch ^ (r & 7)) << 3);
}

// 64x64 * 64x64 symmetric-operand matmul band: wave w computes rows [16w,16w+16).
// A, B given as bf16 hi/lo pairs in swizzled layout. acc[c] += A*B for col-band c.
// Split-2 bf16: (Ah+Al)(Bh+Bl) ~ AhBh + AhBl + AlBh.
__device__ __forceinline__ void mm64(const unsigned short* Ah, const unsigned short* Al,
                                     const unsigned short* Bh, const unsigned short* Bl,
                                     int w, int l, f32x4* acc) {
    const int lc = l & 15, hq = l >> 4;
    const int ar = (w << 4) + lc;
    bf16x8 ah[2], al[2];
    #pragma unroll
    for (int ks = 0; ks < 2; ++ks) {
        ah[ks] = *(const bf16x8*)&Ah[fidx(ar, ks * 4 + hq)];
        al[ks] = *(const bf16x8*)&Al[fidx(ar, ks * 4 + hq)];
    }
    #pragma unroll
    for (int c = 0; c < 4; ++c) {
        const int br = (c << 4) + lc;
        #pragma unroll
        for (int ks = 0; ks < 2; ++ks) {
            bf16x8 bh = *(const bf16x8*)&Bh[fidx(br, ks * 4 + hq)];
            bf16x8 bl = *(const bf16x8*)&Bl[fidx(br, ks * 4 + hq)];
            acc[c] = __builtin_amdgcn_mfma_f32_16x16x32_bf16(ah[ks], bh, acc[c], 0, 0, 0);
            acc[c] = __builtin_amdgcn_mfma_f32_16x16x32_bf16(ah[ks], bl, acc[c], 0, 0, 0);
            acc[c] = __builtin_amdgcn_mfma_f32_16x16x32_bf16(al[ks], bh, acc[c], 0, 0, 0);
        }
    }
}

// LDS: exactly 32 KB (sRed/sTr alias dead B0 region). __launch_bounds__(256,4):
// do NOT force the 102-VGPR cap of min-waves=5 (R4's spill suspect); if natural
// allocation <= 102 the HW still grants 5 blocks/CU since LDS now fits.
__global__ __launch_bounds__(256, 4) void spd_logm_kernel(const float* __restrict__ x,
                                                          float* __restrict__ out) {
    const int m   = blockIdx.x;
    const int tid = threadIdx.x;
    const float* xp = x + (size_t)m * (CH * TT);

    __shared__ __align__(16) unsigned short smem[16384];   // 32768 B exactly
    unsigned short* const B0h = smem;
    unsigned short* const B0l = smem + 4096;
    unsigned short* const B1h = smem + 8192;
    unsigned short* const B1l = smem + 12288;
    float* const sRedf = (float*)smem;         // 64 floats, aliases B0h[0:512B)
    float* const sTrf  = ((float*)smem) + 64;  // 4 floats

    const int w  = tid >> 6;   // wave id -> row band [16w, 16w+16)
    const int l  = tid & 63;
    const int lc = l & 15;     // C-layout col within tile
    const int hq = l >> 4;     // C-layout row quad

    const f32x4 z4 = {0.f, 0.f, 0.f, 0.f};

    // ---------------- Phase 1: G = X * X^T via MFMA ----------------
    // Staging map: 16 lanes cover one row's 64-col tile slice (256 B contiguous
    // per row per instruction -> dense DRAM bursts). Each thread handles rows
    // r0, r0+16, r0+32, r0+48 (pieces j=0..3).
    f32x4 acc[4] = {z4, z4, z4, z4};

    const int g16  = tid & 15;       // col group within row
    const int r0   = tid >> 4;       // base row (0..15)
    const int colf = g16 * 4;        // float col within tile
    const float* xr0 = xp + r0 * TT; // colf added via kb_ only
    // swizzled LDS index for (r0, colf); piece j adds j*1024 (rows +16 keep row&7)
    const int idx0 = (r0 << 6) + ((((colf >> 3) ^ (r0 & 7)) << 3) | (colf & 7));

    float psum[4] = {0.f, 0.f, 0.f, 0.f};
    float4 pf[4];

    #define ISSUE(T) do {                                                          \
        const int kb_ = ((T) << 6) + colf;                                         \
        const bool ok_ = kb_ < TT;                                                 \
        _Pragma("unroll")                                                          \
        for (int j = 0; j < 4; ++j)                                                \
            pf[j] = ok_ ? *(const float4*)(xr0 + j * (16 * TT) + kb_)              \
                        : make_float4(0.f, 0.f, 0.f, 0.f);                         \
    } while (0)

    #define STAGE(XH, XL) do {                                                     \
        _Pragma("unroll")                                                          \
        for (int j = 0; j < 4; ++j) {                                              \
            float4 v = pf[j];                                                      \
            psum[j] += v.x + v.y + v.z + v.w;                                      \
            u16x4 hv, lv;                                                          \
            hv[0] = f2bf(v.x); lv[0] = f2bf(v.x - bf2f(hv[0]));                    \
            hv[1] = f2bf(v.y); lv[1] = f2bf(v.y - bf2f(hv[1]));                    \
            hv[2] = f2bf(v.z); lv[2] = f2bf(v.z - bf2f(hv[2]));                    \
            hv[3] = f2bf(v.w); lv[3] = f2bf(v.w - bf2f(hv[3]));                    \
            *(u16x4*)&XH[idx0 + j * 1024] = hv;                                    \
            *(u16x4*)&XL[idx0 + j * 1024] = lv;                                    \
        }                                                                          \
    } while (0)

    ISSUE(0);   // prologue

    for (int t = 0; t < 16; ++t) {
        unsigned short* Xh = (t & 1) ? B1h : B0h;
        unsigned short* Xl = (t & 1) ? B1l : B0l;

        STAGE(Xh, Xl);                 // waits on pf's vmcnt here
        if (t < 15) ISSUE(t + 1);      // next tile's loads stay in flight

        // drain only LDS writes (NOT the prefetch vmcnt), then raw barrier.
        // Safe: stores(t) target buf[t&1], last read by mm64(t-2); every wave's
        // mm64(t-2) ds_reads drained at its own lgkmcnt(0) before barrier(t-1).
        asm volatile("s_waitcnt lgkmcnt(0)" ::: "memory");
        __builtin_amdgcn_s_barrier();
        __builtin_amdgcn_sched_barrier(0);

        mm64(Xh, Xl, Xh, Xl, w, l, acc);
    }
    #undef ISSUE
    #undef STAGE

    // row sums: 16 lanes per row -> xor-reduce within 16-lane group.
    // sRedf aliases B0 (dead: mm64(15) reads only B1; mm64(14) reads drained).
    #pragma unroll
    for (int j = 0; j < 4; ++j) {
        psum[j] += __shfl_xor(psum[j], 1, 64);
        psum[j] += __shfl_xor(psum[j], 2, 64);
        psum[j] += __shfl_xor(psum[j], 4, 64);
        psum[j] += __shfl_xor(psum[j], 8, 64);
    }
    if (g16 == 0) {
        #pragma unroll
        for (int j = 0; j < 4; ++j) sRedf[r0 + 16 * j] = psum[j];
    }
    __syncthreads();

    // ---------------- cov, trace, E ----------------
    const float invT = 1.f / (float)TT, invTm1 = 1.f / (float)(TT - 1);
    float Srow[4], Scol[4];
    #pragma unroll
    for (int r = 0; r < 4; ++r) Srow[r] = sRedf[(w << 4) + hq * 4 + r];
    #pragma unroll
    for (int c = 0; c < 4; ++c) Scol[c] = sRedf[(c << 4) + lc];

    float covv[4][4];
    float trp = 0.f;
    #pragma unroll
    for (int c = 0; c < 4; ++c)
        #pragma unroll
        for (int r = 0; r < 4; ++r) {
            covv[c][r] = (acc[c][r] - Srow[r] * Scol[c] * invT) * invTm1;
            if (c == w && lc == hq * 4 + r) trp += covv[c][r];
        }
    trp += __shfl_xor(trp, 1, 64);  trp += __shfl_xor(trp, 2, 64);
    trp += __shfl_xor(trp, 4, 64);  trp += __shfl_xor(trp, 8, 64);
    trp += __shfl_xor(trp, 16, 64); trp += __shfl_xor(trp, 32, 64);
    if (l == 0) sTrf[w] = trp;
    __syncthreads();
    const float s    = (sTrf[0] + sTrf[1] + sTrf[2] + sTrf[3]) * (1.f / 64.f);
    const float invs = 1.f / s;
    const float logs = logf(s);
    __syncthreads();   // sRed/sTr fully consumed before E overwrites their alias

    // E = cov/s - I -> B0
    float Ev[4][4], e2v[4][4];
    #pragma unroll
    for (int c = 0; c < 4; ++c)
        #pragma unroll
        for (int r = 0; r < 4; ++r) {
            const int row = (w << 4) + hq * 4 + r, col = (c << 4) + lc;
            const float e = covv[c][r] * invs - ((row == col) ? 1.f : 0.f);
            Ev[c][r] = e;
            const unsigned short h = f2bf(e);
            B0h[sidx(row, col)] = h;
            B0l[sidx(row, col)] = f2bf(e - bf2f(h));
        }
    __syncthreads();

    // ---------------- Phase 2: Paterson-Stockmeyer deg-15 ----------------
    // E^2 -> B1
    f32x4 a2[4] = {z4, z4, z4, z4};
    mm64(B0h, B0l, B0h, B0l, w, l, a2);
    #pragma unroll
    for (int c = 0; c < 4; ++c)
        #pragma unroll
        for (int r = 0; r < 4; ++r) {
            const int row = (w << 4) + hq * 4 + r, col = (c << 4) + lc;
            const float v = a2[c][r];
            e2v[c][r] = v;
            const unsigned short h = f2bf(v);
            B1h[sidx(row, col)] = h;
            B1l[sidx(row, col)] = f2bf(v - bf2f(h));
        }
    __syncthreads();

    // E^3 = E * E^2
    f32x4 a3[4] = {z4, z4, z4, z4};
    mm64(B0h, B0l, B1h, B1l, w, l, a3);
    __syncthreads();   // all reads of E (B0) and E^2 (B1) complete before overwrite

    // P3 = E^3 -> B0 (over E); R init = c12 I + c13 E + c14 E^2 + c15 E^3 -> B1
    #pragma unroll
    for (int c = 0; c < 4; ++c)
        #pragma unroll
        for (int r = 0; r < 4; ++r) {
            const int row = (w << 4) + hq * 4 + r, col = (c << 4) + lc;
            const float e3 = a3[c][r];
            unsigned short h = f2bf(e3);
            B0h[sidx(row, col)] = h;
            B0l[sidx(row, col)] = f2bf(e3 - bf2f(h));
            float rv = (1.f/15.f) * e3 + (-1.f/14.f) * e2v[c][r] + (1.f/13.f) * Ev[c][r]
                     + ((row == col) ? (-1.f/12.f) : 0.f);
            h = f2bf(rv);
            B1h[sidx(row, col)] = h;
            B1l[sidx(row, col)] = f2bf(rv - bf2f(h));
        }
    __syncthreads();

    // Horner: R = E^3*R + (c0 I + c1 E + c2 E^2), j = 3,2,1
    const float CJ[3][3] = {
        { 1.f/9.f, -1.f/10.f,  1.f/11.f },
        {-1.f/6.f,  1.f/7.f,  -1.f/8.f  },
        { 1.f/3.f, -1.f/4.f,   1.f/5.f  },
    };
    #pragma unroll
    for (int jj = 0; jj < 3; ++jj) {
        f32x4 ar[4] = {z4, z4, z4, z4};
        mm64(B0h, B0l, B1h, B1l, w, l, ar);
        __syncthreads();                      // all reads of old R complete
        const float c0 = CJ[jj][0], c1 = CJ[jj][1], c2 = CJ[jj][2];
        #pragma unroll
        for (int c = 0; c < 4; ++c)
            #pragma unroll
            for (int r = 0; r < 4; ++r) {
                const int row = (w << 4) + hq * 4 + r, col = (c << 4) + lc;
                float rv = ar[c][r] + c1 * Ev[c][r] + c2 * e2v[c][r]
                         + ((row == col) ? c0 : 0.f);
                const unsigned short h = f2bf(rv);
                B1h[sidx(row, col)] = h;
                B1l[sidx(row, col)] = f2bf(rv - bf2f(h));
            }
        __syncthreads();                      // new R visible
    }

    // final: p = E^3*R + E - 0.5 E^2 ; logm = p + log(s) I, triu only
    f32x4 aF[4] = {z4, z4, z4, z4};
    mm64(B0h, B0l, B1h, B1l, w, l, aF);
    const size_t ob = (size_t)m * NTRI;
    #pragma unroll
    for (int c = 0; c < 4; ++c)
        #pragma unroll
        for (int r = 0; r < 4; ++r) {
            const int row = (w << 4) + hq * 4 + r, col = (c << 4) + lc;
            if (row <= col) {
                float v = aF[c][r] + Ev[c][r] - 0.5f * e2v[c][r]
                        + ((row == col) ? logs : 0.f);
                out[ob + row * (2 * CH - row + 1) / 2 + (col - row)] = v;
            }
        }
}

extern "C" void kernel_launch(void* const* d_in, const int* in_sizes, int n_in,
                              void* d_out, int out_size, void* d_ws, size_t ws_size,
                              hipStream_t stream) {
    const float* x = (const float*)d_in[0];
    float* out = (float*)d_out;
    const int nm = in_sizes[0] / (CH * TT);   // B*F = 2048
    spd_logm_kernel<<<nm, 256, 0, stream>>>(x, out);
}

// Round 8
// 129.425 us; speedup vs baseline: 1.1259x; 1.0017x over previous
//
#include <hip/hip_runtime.h>
#include <math.h>

#define CH 64
#define TT 1000
#define NTRI 2080

typedef __attribute__((ext_vector_type(8))) short bf16x8;
typedef __attribute__((ext_vector_type(4))) float f32x4;
typedef __attribute__((ext_vector_type(4))) unsigned short u16x4;

// round-half-up f32->bf16: 2 inst, max error 1/2 ulp (same bound as RNE;
// only exact-tie direction differs -> split-2 accuracy class unchanged)
__device__ __forceinline__ unsigned short f2bf_rh(float f) {
    unsigned u = __builtin_bit_cast(unsigned, f);
    return (unsigned short)((u + 0x8000u) >> 16);
}
__device__ __forceinline__ float bf2f(unsigned short h) {
    unsigned u = ((unsigned)h) << 16;
    return __builtin_bit_cast(float, u);
}
// exact split: f ~ bf2f(h) + bf2f(l), returned as (x=h, y=l). |lo| <= 2^-9 |f|.
__device__ __forceinline__ ushort2 split2(float f) {
    const unsigned short h = f2bf_rh(f);
    const unsigned short l = f2bf_rh(f - bf2f(h));
    return make_ushort2(h, l);
}
// element (r,c) of a [64][64] bf16 array, 16B-chunk XOR swizzle (2-way max)
__device__ __forceinline__ int sidx(int r, int c) {
    return (r << 6) + ((((c >> 3) ^ (r & 7)) << 3) | (c & 7));
}
// fragment base: 8 consecutive bf16 of row r, chunk ch (ch = k/8)
__device__ __forceinline__ int fidx(int r, int ch) {
    return (r << 6) + ((ch ^ (r & 7)) << 3);
}

// 64x64 * 64x64 matmul band: wave w computes rows [16w,16w+16).
// Split-2 bf16: (Ah+Al)(Bh+Bl) ~ AhBh + AhBl + AlBh.
// SAME=true: A and B are the SAME matrix; the B-fragment of band c==w is
// bit-identical to the A-fragment (fidx(ar,.)==fidx(br,.) at c==w), so skip
// those 4 ds_read_b128 (20 -> 16 per wave, -20% LDS read traffic).
template<bool SAME>
__device__ __forceinline__ void mm64t(const unsigned short* Ah, const unsigned short* Al,
                                      const unsigned short* Bh, const unsigned short* Bl,
                                      int w, int l, f32x4* acc) {
    const int lc = l & 15, hq = l >> 4;
    const int ar = (w << 4) + lc;
    bf16x8 ah[2], al[2];
    #pragma unroll
    for (int ks = 0; ks < 2; ++ks) {
        ah[ks] = *(const bf16x8*)&Ah[fidx(ar, ks * 4 + hq)];
        al[ks] = *(const bf16x8*)&Al[fidx(ar, ks * 4 + hq)];
    }
    #pragma unroll
    for (int c = 0; c < 4; ++c) {
        const int br = (c << 4) + lc;
        #pragma unroll
        for (int ks = 0; ks < 2; ++ks) {
            bf16x8 bh, bl;
            if (SAME && c == w) {         // wave-uniform branch
                bh = ah[ks]; bl = al[ks];
            } else {
                bh = *(const bf16x8*)&Bh[fidx(br, ks * 4 + hq)];
                bl = *(const bf16x8*)&Bl[fidx(br, ks * 4 + hq)];
            }
            acc[c] = __builtin_amdgcn_mfma_f32_16x16x32_bf16(ah[ks], bh, acc[c], 0, 0, 0);
            acc[c] = __builtin_amdgcn_mfma_f32_16x16x32_bf16(ah[ks], bl, acc[c], 0, 0, 0);
            acc[c] = __builtin_amdgcn_mfma_f32_16x16x32_bf16(al[ks], bh, acc[c], 0, 0, 0);
        }
    }
}

// LDS: exactly 32 KB (sRed/sTr alias dead B0 region).
__global__ __launch_bounds__(256, 4) void spd_logm_kernel(const float* __restrict__ x,
                                                          float* __restrict__ out) {
    const int m   = blockIdx.x;
    const int tid = threadIdx.x;
    const float* xp = x + (size_t)m * (CH * TT);

    __shared__ __align__(16) unsigned short smem[16384];   // 32768 B exactly
    unsigned short* const B0h = smem;
    unsigned short* const B0l = smem + 4096;
    unsigned short* const B1h = smem + 8192;
    unsigned short* const B1l = smem + 12288;
    float* const sRedf = (float*)smem;         // 64 floats, aliases B0h[0:512B)
    float* const sTrf  = ((float*)smem) + 64;  // 4 floats

    const int w  = tid >> 6;   // wave id -> row band [16w, 16w+16)
    const int l  = tid & 63;
    const int lc = l & 15;     // C-layout col within tile
    const int hq = l >> 4;     // C-layout row quad

    const f32x4 z4 = {0.f, 0.f, 0.f, 0.f};

    // ---------------- Phase 1: G = X * X^T via MFMA ----------------
    // Staging map: 16 lanes cover one row's 64-col tile slice (256 B contiguous
    // per row). Each thread handles rows r0, r0+16, r0+32, r0+48 (j=0..3).
    f32x4 acc[4] = {z4, z4, z4, z4};

    const int g16  = tid & 15;       // col group within row
    const int r0   = tid >> 4;       // base row (0..15)
    const int colf = g16 * 4;        // float col within tile
    const float* xr0 = xp + r0 * TT; // colf added via kb_ only
    // swizzled LDS index for (r0, colf); piece j adds j*1024 (rows +16 keep row&7)
    const int idx0 = (r0 << 6) + ((((colf >> 3) ^ (r0 & 7)) << 3) | (colf & 7));

    float psum[4] = {0.f, 0.f, 0.f, 0.f};
    float4 pf[4];

    #define ISSUE(T) do {                                                          \
        const int kb_ = ((T) << 6) + colf;                                         \
        const bool ok_ = kb_ < TT;                                                 \
        _Pragma("unroll")                                                          \
        for (int j = 0; j < 4; ++j)                                                \
            pf[j] = ok_ ? *(const float4*)(xr0 + j * (16 * TT) + kb_)              \
                        : make_float4(0.f, 0.f, 0.f, 0.f);                         \
    } while (0)

    #define STAGE(XH, XL) do {                                                     \
        _Pragma("unroll")                                                          \
        for (int j = 0; j < 4; ++j) {                                              \
            float4 v = pf[j];                                                      \
            psum[j] += v.x + v.y + v.z + v.w;                                      \
            u16x4 hv, lv;                                                          \
            ushort2 s0 = split2(v.x); hv[0] = s0.x; lv[0] = s0.y;                  \
            ushort2 s1 = split2(v.y); hv[1] = s1.x; lv[1] = s1.y;                  \
            ushort2 s2 = split2(v.z); hv[2] = s2.x; lv[2] = s2.y;                  \
            ushort2 s3 = split2(v.w); hv[3] = s3.x; lv[3] = s3.y;                  \
            *(u16x4*)&XH[idx0 + j * 1024] = hv;                                    \
            *(u16x4*)&XL[idx0 + j * 1024] = lv;                                    \
        }                                                                          \
    } while (0)

    ISSUE(0);   // prologue

    for (int t = 0; t < 16; ++t) {
        unsigned short* Xh = (t & 1) ? B1h : B0h;
        unsigned short* Xl = (t & 1) ? B1l : B0l;

        STAGE(Xh, Xl);                 // waits on pf's vmcnt here
        if (t < 15) ISSUE(t + 1);      // next tile's loads stay in flight

        // drain only LDS writes (NOT the prefetch vmcnt), then raw barrier.
        // Safe: stores(t) target buf[t&1], last read by mm64(t-2); every wave's
        // mm64(t-2) ds_reads drained at its own lgkmcnt(0) before barrier(t-1).
        asm volatile("s_waitcnt lgkmcnt(0)" ::: "memory");
        __builtin_amdgcn_s_barrier();
        __builtin_amdgcn_sched_barrier(0);

        mm64t<true>(Xh, Xl, Xh, Xl, w, l, acc);
    }
    #undef ISSUE
    #undef STAGE

    // row sums: 16 lanes per row -> xor-reduce within 16-lane group.
    // sRedf aliases B0 (dead: mm64(15) reads only B1; mm64(14) reads drained).
    #pragma unroll
    for (int j = 0; j < 4; ++j) {
        psum[j] += __shfl_xor(psum[j], 1, 64);
        psum[j] += __shfl_xor(psum[j], 2, 64);
        psum[j] += __shfl_xor(psum[j], 4, 64);
        psum[j] += __shfl_xor(psum[j], 8, 64);
    }
    if (g16 == 0) {
        #pragma unroll
        for (int j = 0; j < 4; ++j) sRedf[r0 + 16 * j] = psum[j];
    }
    __syncthreads();

    // ---------------- cov, trace, E ----------------
    const float invT = 1.f / (float)TT, invTm1 = 1.f / (float)(TT - 1);
    float Srow[4], Scol[4];
    #pragma unroll
    for (int r = 0; r < 4; ++r) Srow[r] = sRedf[(w << 4) + hq * 4 + r];
    #pragma unroll
    for (int c = 0; c < 4; ++c) Scol[c] = sRedf[(c << 4) + lc];

    float covv[4][4];
    float trp = 0.f;
    #pragma unroll
    for (int c = 0; c < 4; ++c)
        #pragma unroll
        for (int r = 0; r < 4; ++r) {
            covv[c][r] = (acc[c][r] - Srow[r] * Scol[c] * invT) * invTm1;
            if (c == w && lc == hq * 4 + r) trp += covv[c][r];
        }
    trp += __shfl_xor(trp, 1, 64);  trp += __shfl_xor(trp, 2, 64);
    trp += __shfl_xor(trp, 4, 64);  trp += __shfl_xor(trp, 8, 64);
    trp += __shfl_xor(trp, 16, 64); trp += __shfl_xor(trp, 32, 64);
    if (l == 0) sTrf[w] = trp;
    __syncthreads();
    const float s    = (sTrf[0] + sTrf[1] + sTrf[2] + sTrf[3]) * (1.f / 64.f);
    const float invs = 1.f / s;
    const float logs = logf(s);
    __syncthreads();   // sRed/sTr fully consumed before E overwrites their alias

    // E = cov/s - I -> B0
    float Ev[4][4], e2v[4][4];
    #pragma unroll
    for (int c = 0; c < 4; ++c)
        #pragma unroll
        for (int r = 0; r < 4; ++r) {
            const int row = (w << 4) + hq * 4 + r, col = (c << 4) + lc;
            const float e = covv[c][r] * invs - ((row == col) ? 1.f : 0.f);
            Ev[c][r] = e;
            const ushort2 se = split2(e);
            B0h[sidx(row, col)] = se.x;
            B0l[sidx(row, col)] = se.y;
        }
    __syncthreads();

    // ---------------- Phase 2: Paterson-Stockmeyer deg-15 ----------------
    // E^2 -> B1  (A==B==E: symmetric-operand fast path)
    f32x4 a2[4] = {z4, z4, z4, z4};
    mm64t<true>(B0h, B0l, B0h, B0l, w, l, a2);
    #pragma unroll
    for (int c = 0; c < 4; ++c)
        #pragma unroll
        for (int r = 0; r < 4; ++r) {
            const int row = (w << 4) + hq * 4 + r, col = (c << 4) + lc;
            const float v = a2[c][r];
            e2v[c][r] = v;
            const ushort2 sv = split2(v);
            B1h[sidx(row, col)] = sv.x;
            B1l[sidx(row, col)] = sv.y;
        }
    __syncthreads();

    // E^3 = E * E^2
    f32x4 a3[4] = {z4, z4, z4, z4};
    mm64t<false>(B0h, B0l, B1h, B1l, w, l, a3);
    __syncthreads();   // all reads of E (B0) and E^2 (B1) complete before overwrite

    // P3 = E^3 -> B0 (over E); R init = c12 I + c13 E + c14 E^2 + c15 E^3 -> B1
    #pragma unroll
    for (int c = 0; c < 4; ++c)
        #pragma unroll
        for (int r = 0; r < 4; ++r) {
            const int row = (w << 4) + hq * 4 + r, col = (c << 4) + lc;
            const float e3 = a3[c][r];
            const ushort2 s3 = split2(e3);
            B0h[sidx(row, col)] = s3.x;
            B0l[sidx(row, col)] = s3.y;
            float rv = (1.f/15.f) * e3 + (-1.f/14.f) * e2v[c][r] + (1.f/13.f) * Ev[c][r]
                     + ((row == col) ? (-1.f/12.f) : 0.f);
            const ushort2 sr = split2(rv);
            B1h[sidx(row, col)] = sr.x;
            B1l[sidx(row, col)] = sr.y;
        }
    __syncthreads();

    // Horner: R = E^3*R + (c0 I + c1 E + c2 E^2), j = 3,2,1
    const float CJ[3][3] = {
        { 1.f/9.f, -1.f/10.f,  1.f/11.f },
        {-1.f/6.f,  1.f/7.f,  -1.f/8.f  },
        { 1.f/3.f, -1.f/4.f,   1.f/5.f  },
    };
    #pragma unroll
    for (int jj = 0; jj < 3; ++jj) {
        f32x4 ar[4] = {z4, z4, z4, z4};
        mm64t<false>(B0h, B0l, B1h, B1l, w, l, ar);
        __syncthreads();                      // all reads of old R complete
        const float c0 = CJ[jj][0], c1 = CJ[jj][1], c2 = CJ[jj][2];
        #pragma unroll
        for (int c = 0; c < 4; ++c)
            #pragma unroll
            for (int r = 0; r < 4; ++r) {
                const int row = (w << 4) + hq * 4 + r, col = (c << 4) + lc;
                float rv = ar[c][r] + c1 * Ev[c][r] + c2 * e2v[c][r]
                         + ((row == col) ? c0 : 0.f);
                const ushort2 sr = split2(rv);
                B1h[sidx(row, col)] = sr.x;
                B1l[sidx(row, col)] = sr.y;
            }
        __syncthreads();                      // new R visible
    }

    // final: p = E^3*R + E - 0.5 E^2 ; logm = p + log(s) I, triu only
    f32x4 aF[4] = {z4, z4, z4, z4};
    mm64t<false>(B0h, B0l, B1h, B1l, w, l, aF);
    const size_t ob = (size_t)m * NTRI;
    #pragma unroll
    for (int c = 0; c < 4; ++c)
        #pragma unroll
        for (int r = 0; r < 4; ++r) {
            const int row = (w << 4) + hq * 4 + r, col = (c << 4) + lc;
            if (row <= col) {
                float v = aF[c][r] + Ev[c][r] - 0.5f * e2v[c][r]
                        + ((row == col) ? logs : 0.f);
                out[ob + row * (2 * CH - row + 1) / 2 + (col - row)] = v;
            }
        }
}

extern "C" void kernel_launch(void* const* d_in, const int* in_sizes, int n_in,
                              void* d_out, int out_size, void* d_ws, size_t ws_size,
                              hipStream_t stream) {
    const float* x = (const float*)d_in[0];
    float* out = (float*)d_out;
    const int nm = in_sizes[0] / (CH * TT);   // B*F = 2048
    spd_logm_kernel<<<nm, 256, 0, stream>>>(x, out);
}

// Round 9
// 128.390 us; speedup vs baseline: 1.1349x; 1.0081x over previous
//
#include <hip/hip_runtime.h>
#include <math.h>

#define CH 64
#define TT 1000
#define NTRI 2080

typedef __attribute__((ext_vector_type(8))) short bf16x8;
typedef __attribute__((ext_vector_type(4))) float f32x4;
typedef __attribute__((ext_vector_type(4))) unsigned short u16x4;

// round-half-up f32->bf16: 2 inst, max error 1/2 ulp (same bound as RNE)
__device__ __forceinline__ unsigned short f2bf_rh(float f) {
    unsigned u = __builtin_bit_cast(unsigned, f);
    return (unsigned short)((u + 0x8000u) >> 16);
}
__device__ __forceinline__ float bf2f(unsigned short h) {
    unsigned u = ((unsigned)h) << 16;
    return __builtin_bit_cast(float, u);
}
// exact split: f ~ bf2f(h) + bf2f(l), returned as (x=h, y=l). |lo| <= 2^-9 |f|.
__device__ __forceinline__ ushort2 split2(float f) {
    const unsigned short h = f2bf_rh(f);
    const unsigned short l = f2bf_rh(f - bf2f(h));
    return make_ushort2(h, l);
}
// element (r,c) of a [64][64] bf16 array, 16B-chunk XOR swizzle (2-way max)
__device__ __forceinline__ int sidx(int r, int c) {
    return (r << 6) + ((((c >> 3) ^ (r & 7)) << 3) | (c & 7));
}
// fragment base: 8 consecutive bf16 of row r, chunk ch (ch = k/8)
__device__ __forceinline__ int fidx(int r, int ch) {
    return (r << 6) + ((ch ^ (r & 7)) << 3);
}

// 64x64 * 64x64 matmul band: wave w computes rows [16w,16w+16).
// Split-2 bf16: (Ah+Al)(Bh+Bl) ~ AhBh + AhBl + AlBh.
// SAME=true: A and B are the SAME matrix; B-fragment of band c==w is
// bit-identical to the A-fragment -> skip those 4 ds_read_b128.
template<bool SAME>
__device__ __forceinline__ void mm64t(const unsigned short* Ah, const unsigned short* Al,
                                      const unsigned short* Bh, const unsigned short* Bl,
                                      int w, int l, f32x4* acc) {
    const int lc = l & 15, hq = l >> 4;
    const int ar = (w << 4) + lc;
    bf16x8 ah[2], al[2];
    #pragma unroll
    for (int ks = 0; ks < 2; ++ks) {
        ah[ks] = *(const bf16x8*)&Ah[fidx(ar, ks * 4 + hq)];
        al[ks] = *(const bf16x8*)&Al[fidx(ar, ks * 4 + hq)];
    }
    #pragma unroll
    for (int c = 0; c < 4; ++c) {
        const int br = (c << 4) + lc;
        #pragma unroll
        for (int ks = 0; ks < 2; ++ks) {
            bf16x8 bh, bl;
            if (SAME && c == w) {         // wave-uniform branch
                bh = ah[ks]; bl = al[ks];
            } else {
                bh = *(const bf16x8*)&Bh[fidx(br, ks * 4 + hq)];
                bl = *(const bf16x8*)&Bl[fidx(br, ks * 4 + hq)];
            }
            acc[c] = __builtin_amdgcn_mfma_f32_16x16x32_bf16(ah[ks], bh, acc[c], 0, 0, 0);
            acc[c] = __builtin_amdgcn_mfma_f32_16x16x32_bf16(ah[ks], bl, acc[c], 0, 0, 0);
            acc[c] = __builtin_amdgcn_mfma_f32_16x16x32_bf16(al[ks], bh, acc[c], 0, 0, 0);
        }
    }
}

// LDS: exactly 32 KB (sRed/sTr alias dead B0 region).
__global__ __launch_bounds__(256, 4) void spd_logm_kernel(const float* __restrict__ x,
                                                          float* __restrict__ out) {
    const int m   = blockIdx.x;
    const int tid = threadIdx.x;

    // ---- Phase-decorrelation stagger -------------------------------------
    // Co-resident blocks start in lockstep and run identical per-tile work,
    // so their no-issue windows (convert/barrier/mm64) align -> HBM channel
    // idles ~25% of each ~2.8us tile period. Offset block (bid&3) by
    // k * ~0.7us (s_memrealtime = 100 MHz constant clock, 70 ticks).
    {
        const unsigned phase = blockIdx.x & 3u;
        if (phase) {
            const unsigned long long tgt =
                __builtin_amdgcn_s_memrealtime() + (unsigned long long)(phase * 70u);
            while (__builtin_amdgcn_s_memrealtime() < tgt) { }
        }
    }

    const float* xp = x + (size_t)m * (CH * TT);

    __shared__ __align__(16) unsigned short smem[16384];   // 32768 B exactly
    unsigned short* const B0h = smem;
    unsigned short* const B0l = smem + 4096;
    unsigned short* const B1h = smem + 8192;
    unsigned short* const B1l = smem + 12288;
    float* const sRedf = (float*)smem;         // 64 floats, aliases B0h[0:512B)
    float* const sTrf  = ((float*)smem) + 64;  // 4 floats

    const int w  = tid >> 6;   // wave id -> row band [16w, 16w+16)
    const int l  = tid & 63;
    const int lc = l & 15;     // C-layout col within tile
    const int hq = l >> 4;     // C-layout row quad

    const f32x4 z4 = {0.f, 0.f, 0.f, 0.f};

    // ---------------- Phase 1: G = X * X^T via MFMA ----------------
    // R0 staging map (best measured): thread -> row srow, col-slice sq.
    f32x4 acc[4] = {z4, z4, z4, z4};

    const int srow = tid >> 2, sq = tid & 3;
    const float* xrow = xp + srow * TT;
    float psum = 0.f;

    // prologue: prefetch tile 0 (cols 0..63, all < TT)
    float4 pf0 = *(const float4*)&xrow[sq * 4];
    float4 pf1 = *(const float4*)&xrow[sq * 4 + 16];
    float4 pf2 = *(const float4*)&xrow[sq * 4 + 32];
    float4 pf3 = *(const float4*)&xrow[sq * 4 + 48];

    for (int t = 0; t < 16; ++t) {
        unsigned short* Xh = (t & 1) ? B1h : B0h;
        unsigned short* Xl = (t & 1) ? B1l : B0l;

        float4 vv[4] = {pf0, pf1, pf2, pf3};
        #pragma unroll
        for (int q4 = 0; q4 < 4; ++q4) {
            float4 v = vv[q4];
            psum += v.x + v.y + v.z + v.w;
            const int kl = sq * 4 + q4 * 16;
            u16x4 hv, lv;
            ushort2 s0 = split2(v.x); hv[0] = s0.x; lv[0] = s0.y;
            ushort2 s1 = split2(v.y); hv[1] = s1.x; lv[1] = s1.y;
            ushort2 s2 = split2(v.z); hv[2] = s2.x; lv[2] = s2.y;
            ushort2 s3 = split2(v.w); hv[3] = s3.x; lv[3] = s3.y;
            const int idx = (srow << 6) + ((((kl >> 3) ^ (srow & 7)) << 3) | (kl & 7));
            *(u16x4*)&Xh[idx] = hv;
            *(u16x4*)&Xl[idx] = lv;
        }

        if (t < 15) {
            const int kb = ((t + 1) << 6) + sq * 4;
            pf0 = (kb      < TT) ? *(const float4*)&xrow[kb]      : make_float4(0.f, 0.f, 0.f, 0.f);
            pf1 = (kb + 16 < TT) ? *(const float4*)&xrow[kb + 16] : make_float4(0.f, 0.f, 0.f, 0.f);
            pf2 = (kb + 32 < TT) ? *(const float4*)&xrow[kb + 32] : make_float4(0.f, 0.f, 0.f, 0.f);
            pf3 = (kb + 48 < TT) ? *(const float4*)&xrow[kb + 48] : make_float4(0.f, 0.f, 0.f, 0.f);
        }

        // drain only LDS writes (NOT the prefetch vmcnt), then raw barrier.
        // Safe: stores(t) target buf[t&1], last read by mm64(t-2); every wave's
        // mm64(t-2) ds_reads drained at its own lgkmcnt(0) before barrier(t-1).
        asm volatile("s_waitcnt lgkmcnt(0)" ::: "memory");
        __builtin_amdgcn_s_barrier();
        __builtin_amdgcn_sched_barrier(0);

        mm64t<true>(Xh, Xl, Xh, Xl, w, l, acc);
    }

    // row sums (4 threads per row are adjacent lanes).
    // sRedf aliases B0 row 0-7 area; mm64(15) reads only B1; mm64(14) drained.
    psum += __shfl_xor(psum, 1, 64);
    psum += __shfl_xor(psum, 2, 64);
    if (sq == 0) sRedf[srow] = psum;
    __syncthreads();

    // ---------------- cov, trace, E ----------------
    const float invT = 1.f / (float)TT, invTm1 = 1.f / (float)(TT - 1);
    float Srow[4], Scol[4];
    #pragma unroll
    for (int r = 0; r < 4; ++r) Srow[r] = sRedf[(w << 4) + hq * 4 + r];
    #pragma unroll
    for (int c = 0; c < 4; ++c) Scol[c] = sRedf[(c << 4) + lc];

    float covv[4][4];
    float trp = 0.f;
    #pragma unroll
    for (int c = 0; c < 4; ++c)
        #pragma unroll
        for (int r = 0; r < 4; ++r) {
            covv[c][r] = (acc[c][r] - Srow[r] * Scol[c] * invT) * invTm1;
            if (c == w && lc == hq * 4 + r) trp += covv[c][r];
        }
    trp += __shfl_xor(trp, 1, 64);  trp += __shfl_xor(trp, 2, 64);
    trp += __shfl_xor(trp, 4, 64);  trp += __shfl_xor(trp, 8, 64);
    trp += __shfl_xor(trp, 16, 64); trp += __shfl_xor(trp, 32, 64);
    if (l == 0) sTrf[w] = trp;
    __syncthreads();
    const float s    = (sTrf[0] + sTrf[1] + sTrf[2] + sTrf[3]) * (1.f / 64.f);
    const float invs = 1.f / s;
    const float logs = logf(s);
    __syncthreads();   // sRed/sTr fully consumed before E overwrites their alias

    // E = cov/s - I -> B0
    float Ev[4][4], e2v[4][4];
    #pragma unroll
    for (int c = 0; c < 4; ++c)
        #pragma unroll
        for (int r = 0; r < 4; ++r) {
            const int row = (w << 4) + hq * 4 + r, col = (c << 4) + lc;
            const float e = covv[c][r] * invs - ((row == col) ? 1.f : 0.f);
            Ev[c][r] = e;
            const ushort2 se = split2(e);
            B0h[sidx(row, col)] = se.x;
            B0l[sidx(row, col)] = se.y;
        }
    __syncthreads();

    // ---------------- Phase 2: Paterson-Stockmeyer deg-15 ----------------
    // E^2 -> B1  (A==B==E: symmetric-operand fast path)
    f32x4 a2[4] = {z4, z4, z4, z4};
    mm64t<true>(B0h, B0l, B0h, B0l, w, l, a2);
    #pragma unroll
    for (int c = 0; c < 4; ++c)
        #pragma unroll
        for (int r = 0; r < 4; ++r) {
            const int row = (w << 4) + hq * 4 + r, col = (c << 4) + lc;
            const float v = a2[c][r];
            e2v[c][r] = v;
            const ushort2 sv = split2(v);
            B1h[sidx(row, col)] = sv.x;
            B1l[sidx(row, col)] = sv.y;
        }
    __syncthreads();

    // E^3 = E * E^2
    f32x4 a3[4] = {z4, z4, z4, z4};
    mm64t<false>(B0h, B0l, B1h, B1l, w, l, a3);
    __syncthreads();   // all reads of E (B0) and E^2 (B1) complete before overwrite

    // P3 = E^3 -> B0 (over E); R init = c12 I + c13 E + c14 E^2 + c15 E^3 -> B1
    #pragma unroll
    for (int c = 0; c < 4; ++c)
        #pragma unroll
        for (int r = 0; r < 4; ++r) {
            const int row = (w << 4) + hq * 4 + r, col = (c << 4) + lc;
            const float e3 = a3[c][r];
            const ushort2 s3 = split2(e3);
            B0h[sidx(row, col)] = s3.x;
            B0l[sidx(row, col)] = s3.y;
            float rv = (1.f/15.f) * e3 + (-1.f/14.f) * e2v[c][r] + (1.f/13.f) * Ev[c][r]
                     + ((row == col) ? (-1.f/12.f) : 0.f);
            const ushort2 sr = split2(rv);
            B1h[sidx(row, col)] = sr.x;
            B1l[sidx(row, col)] = sr.y;
        }
    __syncthreads();

    // Horner: R = E^3*R + (c0 I + c1 E + c2 E^2), j = 3,2,1
    const float CJ[3][3] = {
        { 1.f/9.f, -1.f/10.f,  1.f/11.f },
        {-1.f/6.f,  1.f/7.f,  -1.f/8.f  },
        { 1.f/3.f, -1.f/4.f,   1.f/5.f  },
    };
    #pragma unroll
    for (int jj = 0; jj < 3; ++jj) {
        f32x4 ar[4] = {z4, z4, z4, z4};
        mm64t<false>(B0h, B0l, B1h, B1l, w, l, ar);
        __syncthreads();                      // all reads of old R complete
        const float c0 = CJ[jj][0], c1 = CJ[jj][1], c2 = CJ[jj][2];
        #pragma unroll
        for (int c = 0; c < 4; ++c)
            #pragma unroll
            for (int r = 0; r < 4; ++r) {
                const int row = (w << 4) + hq * 4 + r, col = (c << 4) + lc;
                float rv = ar[c][r] + c1 * Ev[c][r] + c2 * e2v[c][r]
                         + ((row == col) ? c0 : 0.f);
                const ushort2 sr = split2(rv);
                B1h[sidx(row, col)] = sr.x;
                B1l[sidx(row, col)] = sr.y;
            }
        __syncthreads();                      // new R visible
    }

    // final: p = E^3*R + E - 0.5 E^2 ; logm = p + log(s) I, triu only
    f32x4 aF[4] = {z4, z4, z4, z4};
    mm64t<false>(B0h, B0l, B1h, B1l, w, l, aF);
    const size_t ob = (size_t)m * NTRI;
    #pragma unroll
    for (int c = 0; c < 4; ++c)
        #pragma unroll
        for (int r = 0; r < 4; ++r) {
            const int row = (w << 4) + hq * 4 + r, col = (c << 4) + lc;
            if (row <= col) {
                float v = aF[c][r] + Ev[c][r] - 0.5f * e2v[c][r]
                        + ((row == col) ? logs : 0.f);
                out[ob + row * (2 * CH - row + 1) / 2 + (col - row)] = v;
            }
        }
}

extern "C" void kernel_launch(void* const* d_in, const int* in_sizes, int n_in,
                              void* d_out, int out_size, void* d_ws, size_t ws_size,
                              hipStream_t stream) {
    const float* x = (const float*)d_in[0];
    float* out = (float*)d_out;
    const int nm = in_sizes[0] / (CH * TT);   // B*F = 2048
    spd_logm_kernel<<<nm, 256, 0, stream>>>(x, out);
}